// Round 6
// baseline (2375.133 us; speedup 1.0000x reference)
//
#include <hip/hip_runtime.h>
#include <hip/hip_bf16.h>

// GraphEncoder: NNConv (edge-MLP 16->256->1024->1024 + einsum + scatter) + 3x GINConv.
// R5 post-mortem: VALU GEMM also gave bit-identical 11.765625 -> GEMM exonerated.
// Root cause: d_out is FLOAT32 (reference output dtype, per harness contract); we
// were writing bf16 u16s. Harness-read fp32 = two adjacent bf16s mashed -> identical
// bytes across rounds (bf16 rounding absorbs MFMA-vs-VALU deltas). R6: write fp32
// to d_out. Keep MFMA GEMM with m92-verified explicit ds_write_b128 staging (R4).

#define NN 50000
#define EE 200000

typedef unsigned short u16;
typedef __attribute__((ext_vector_type(8))) short frag8;
typedef __attribute__((ext_vector_type(4))) float f32x4;

__device__ __forceinline__ float bf2f(u16 u) {
    union { unsigned int i; float f; } v; v.i = ((unsigned int)u) << 16; return v.f;
}
__device__ __forceinline__ u16 f2bf(float f) {
    union { float f; unsigned int i; } v; v.f = f;
    return (u16)((v.i + 0x7fffu + ((v.i >> 16) & 1u)) >> 16);
}
__device__ __forceinline__ float eluf(float v) {
    return v > 0.f ? v : __expf(v) - 1.f;
}

// ---------------- float dtype probe: fp32-as-bf16 shows crazy exponents ----------------
__global__ void probe_f32(const u16* __restrict__ raw, int* __restrict__ cnt) {
    int t = threadIdx.x;  // single block of 256
    int c = 0;
    for (int j = t; j < 1024; j += 256) {
        unsigned e = (raw[j] >> 7) & 0xFF;
        if (e >= 0xBF) c++;   // |v| >= 2^64: never in genuine N(0,1)-ish bf16 data
    }
    if (c) atomicAdd(cnt, c);
}
// dst bf16 <- src (fp32 if *cnt>=8 else bf16 passthrough)
__global__ void cvt_bf16(const void* __restrict__ src, u16* __restrict__ dst, long n,
                         const int* __restrict__ cnt) {
    long i = (long)blockIdx.x * 256 + threadIdx.x;
    if (i >= n) return;
    if (*cnt >= 8) dst[i] = f2bf(((const float*)src)[i]);
    else           dst[i] = ((const u16*)src)[i];
}

// ---------------- edge_index layout probe + conversion ----------------
__global__ void detect_idx64(const unsigned long long* __restrict__ p, int* __restrict__ flag) {
    long t = (long)blockIdx.x * 256 + threadIdx.x;
    if (t < EE) {
        unsigned long long v = p[t];
        if (v >> 31) atomicOr(flag, 1);   // int32-packed pairs have high bits set
    }
}
__global__ void convert_idx(const void* __restrict__ raw, const int* __restrict__ flag,
                            int* __restrict__ s_out, int* __restrict__ d_out) {
    long t = (long)blockIdx.x * 256 + threadIdx.x;
    if (t >= EE) return;
    if (*flag) {  // int32 layout
        const int* q = (const int*)raw;
        s_out[t] = q[t];
        d_out[t] = q[EE + t];
    } else {      // int64 layout
        const long long* q = (const long long*)raw;
        s_out[t] = (int)q[t];
        d_out[t] = (int)q[EE + t];
    }
}

// ---------------- generic bf16 transpose [K,N] -> [N,K] ----------------
__global__ void transpose_bf16(const u16* __restrict__ in, u16* __restrict__ out, int K, int N) {
    long idx = (long)blockIdx.x * 256 + threadIdx.x;
    if (idx < (long)K * N) {
        int k = (int)(idx / N);
        int n = (int)(idx % N);
        out[(long)n * K + k] = in[idx];
    }
}

// ---------------- edge MLP layer 1: h1 = ELU(attr @ W1 + b1), K=16, N=256 ----------------
__global__ void edge_mlp1(const u16* __restrict__ attr, const u16* __restrict__ w1,
                          const u16* __restrict__ b1, u16* __restrict__ h1, int ce) {
    __shared__ u16 sa[256];
    const int t = threadIdx.x;
    const int e0 = blockIdx.x * 16;
    const int cnt = min(16, ce - e0);
    sa[t] = (t < cnt * 16) ? attr[(long)e0 * 16 + t] : (u16)0;
    float w[16];
    #pragma unroll
    for (int i = 0; i < 16; ++i) w[i] = bf2f(w1[i * 256 + t]);
    const float bb = bf2f(b1[t]);
    __syncthreads();
    for (int e = 0; e < cnt; ++e) {
        float v = bb;
        #pragma unroll
        for (int i = 0; i < 16; ++i) v += bf2f(sa[e * 16 + i]) * w[i];
        h1[(long)(e0 + e) * 256 + t] = f2bf(eluf(v));
    }
}

// ---- stage 128x32 bf16 tile: explicit global->reg->ds_write_b128 (m92 pattern) ----
__device__ __forceinline__ void stage_tile(const u16* g, long row_base, long max_row,
                                           int kstride, int k0, u16* s, int t) {
    #pragma unroll
    for (int j = 0; j < 2; ++j) {
        int c = t + 256 * j;                 // chunk id 0..511 (16B each)
        long r = row_base + (c >> 2);
        if (r > max_row) r = max_row;        // tail clamp (masked at C store)
        frag8 v = *(const frag8*)(g + r * (long)kstride + k0 + (c & 3) * 8);
        *(frag8*)(s + (long)c * 8) = v;      // ds_write_b128
    }
}

// C = ELU(A[M,K] @ BT[N,K]^T + bias), bf16 out. N mult of 128, K mult of 32.
// blockIdx.x = N-tile (fast), blockIdx.y = M-tile -> consecutive blocks share A-tile.
__global__ __launch_bounds__(256)
void gemm_bt_bias_elu(const u16* __restrict__ A, const u16* __restrict__ BT,
                      const u16* __restrict__ bias, u16* __restrict__ C,
                      int M, int K, int N) {
    __shared__ __align__(16) u16 sA[128 * 32];
    __shared__ __align__(16) u16 sB[128 * 32];
    const int t = threadIdx.x;
    const int lane = t & 63;
    const int wave = t >> 6;
    const int wr = wave >> 1, wc = wave & 1;
    const int quad = lane >> 4, l16 = lane & 15;
    const long m0 = (long)blockIdx.y * 128;
    const int n0 = blockIdx.x * 128;

    f32x4 acc[4][4];
    const f32x4 z4 = {0.f, 0.f, 0.f, 0.f};
    #pragma unroll
    for (int mi = 0; mi < 4; ++mi)
        #pragma unroll
        for (int ni = 0; ni < 4; ++ni)
            acc[mi][ni] = z4;

    for (int k0 = 0; k0 < K; k0 += 32) {
        stage_tile(A, m0, (long)M - 1, K, k0, sA, t);
        stage_tile(BT, n0, (long)N - 1, K, k0, sB, t);
        __syncthreads();
        frag8 af[4], bfv[4];
        #pragma unroll
        for (int mi = 0; mi < 4; ++mi)
            af[mi] = *(const frag8*)(sA + (wr * 64 + mi * 16 + l16) * 32 + quad * 8);
        #pragma unroll
        for (int ni = 0; ni < 4; ++ni)
            bfv[ni] = *(const frag8*)(sB + (wc * 64 + ni * 16 + l16) * 32 + quad * 8);
        #pragma unroll
        for (int mi = 0; mi < 4; ++mi)
            #pragma unroll
            for (int ni = 0; ni < 4; ++ni)
                acc[mi][ni] = __builtin_amdgcn_mfma_f32_16x16x32_bf16(af[mi], bfv[ni], acc[mi][ni], 0, 0, 0);
        __syncthreads();
    }

    #pragma unroll
    for (int mi = 0; mi < 4; ++mi) {
        #pragma unroll
        for (int r = 0; r < 4; ++r) {
            long row = m0 + wr * 64 + mi * 16 + quad * 4 + r;  // C/D: row = quad*4+reg
            if (row < M) {
                #pragma unroll
                for (int ni = 0; ni < 4; ++ni) {
                    int col = n0 + wc * 64 + ni * 16 + l16;    // C/D: col = lane&15
                    float v = acc[mi][ni][r] + bf2f(bias[col]);
                    C[row * (long)N + col] = f2bf(eluf(v));
                }
            }
        }
    }
}

// msg[e,o] = sum_i x[src[e],i] * we[e, i*64+o]; atomicAdd into agg[dst[e],o]
__global__ void nnconv_msg(const u16* __restrict__ we, const u16* __restrict__ x,
                           const int* __restrict__ src, const int* __restrict__ dst,
                           float* __restrict__ agg, int ce) {
    long idx = (long)blockIdx.x * 256 + threadIdx.x;
    if (idx >= (long)ce * 64) return;
    int o = (int)(idx & 63);
    long e = idx >> 6;
    const u16* wr = we + e * 1024;
    const u16* xr = x + (long)src[e] * 16;
    float v = 0.f;
    #pragma unroll
    for (int i = 0; i < 16; ++i)
        v += bf2f(xr[i]) * bf2f(wr[i * 64 + o]);
    atomicAdd(&agg[(long)dst[e] * 64 + o], v);
}

// ---- x_cur = x @ root_w + root_b + agg (in-place on agg); out[:,:,0] fp32 ----
__global__ void add_root_out(const u16* __restrict__ x, const u16* __restrict__ rw,
                             const u16* __restrict__ rb, float* __restrict__ xcur,
                             float* __restrict__ out) {
    long idx = (long)blockIdx.x * 256 + threadIdx.x;
    if (idx >= (long)NN * 64) return;
    int d = (int)(idx & 63);
    long n = idx >> 6;
    float v = bf2f(rb[d]);
    #pragma unroll
    for (int i = 0; i < 16; ++i)
        v += bf2f(x[n * 16 + i]) * bf2f(rw[i * 64 + d]);
    v += xcur[idx];
    xcur[idx] = v;
    out[n * 256 + (long)d * 4] = v;   // fp32 output
}

__global__ void elu_bf16(const float* __restrict__ in, u16* __restrict__ o, long n) {
    long idx = (long)blockIdx.x * 256 + threadIdx.x;
    if (idx < n) o[idx] = f2bf(eluf(in[idx]));
}

__global__ void gin_scatter(const u16* __restrict__ xin, const int* __restrict__ src,
                            const int* __restrict__ dst, float* __restrict__ nbr) {
    long idx = (long)blockIdx.x * 256 + threadIdx.x;
    if (idx >= (long)EE * 64) return;
    int d = (int)(idx & 63);
    long e = idx >> 6;
    atomicAdd(&nbr[(long)dst[e] * 64 + d], bf2f(xin[(long)src[e] * 64 + d]));
}

__global__ void gin_combine(const u16* __restrict__ xin, const float* __restrict__ nbr,
                            u16* __restrict__ hin, long n) {
    long idx = (long)blockIdx.x * 256 + threadIdx.x;
    if (idx < n) hin[idx] = f2bf(bf2f(xin[idx]) + nbr[idx]);
}

// x_cur = hg2 @ gin_w3[l] + b3; chunked over nodes. w3t_l is [64][256]. fp32 out.
__global__ void gin_out(const u16* __restrict__ hg2, const u16* __restrict__ w3t_l,
                        const u16* __restrict__ b3_l, float* __restrict__ xcur,
                        float* __restrict__ out, int lidx, int cn) {
    long idx = (long)blockIdx.x * 256 + threadIdx.x;
    if (idx >= (long)cn * 64) return;
    int d = (int)(idx & 63);
    long n = idx >> 6;
    const u16* hrow = hg2 + n * 256;           // wave-uniform (broadcast loads)
    const u16* wrow = w3t_l + (long)d * 256;   // per-lane contiguous
    float v = bf2f(b3_l[d]);
    #pragma unroll 4
    for (int k8 = 0; k8 < 32; ++k8) {
        frag8 hv = *(const frag8*)(hrow + k8 * 8);
        frag8 wv = *(const frag8*)(wrow + k8 * 8);
        #pragma unroll
        for (int j = 0; j < 8; ++j)
            v += bf2f((u16)hv[j]) * bf2f((u16)wv[j]);
    }
    xcur[idx] = v;
    out[n * 256 + (long)d * 4 + lidx] = v;   // fp32 output
}

extern "C" void kernel_launch(void* const* d_in, const int* in_sizes, int n_in,
                              void* d_out, int out_size, void* d_ws, size_t ws_size,
                              hipStream_t stream) {
    (void)in_sizes; (void)n_in; (void)out_size;
    const void* eidx = d_in[1];
    float* out = (float*)d_out;   // reference output dtype = float32

    char* ws = (char*)d_ws;
    size_t off = 0;
    auto alloc = [&](size_t bytes) {
        char* p = ws + off;
        off += (bytes + 255) & ~(size_t)255;
        return p;
    };
    // ---- persistent ----
    int* src32 = (int*)alloc((size_t)EE * 4);
    int* dst32 = (int*)alloc((size_t)EE * 4);
    int* flag  = (int*)alloc(256);
    int* cnt   = (int*)alloc(256);
    // bf16-normalized input copies (d_in index, element count)
    const int cv_idx[16] = {0, 2, 3, 4, 5, 6, 7, 8, 9, 10, 11, 12, 13, 14, 15, 16};
    const long cv_n[16]  = {800000, 3200000, 4096, 256, 262144, 1024, 1048576, 1024,
                            1024, 64, 49152, 768, 196608, 768, 49152, 192};
    u16* cv[16];
    for (int i = 0; i < 16; ++i) cv[i] = (u16*)alloc((size_t)cv_n[i] * 2);
    u16 *xc = cv[0], *eac = cv[1], *w1c = cv[2], *b1c = cv[3], *w2c = cv[4], *b2c = cv[5],
        *w3c = cv[6], *b3c = cv[7], *rwc = cv[8], *rbc = cv[9],
        *g1c = cv[10], *gb1c = cv[11], *g2c = cv[12], *gb2c = cv[13], *g3c = cv[14], *gb3c = cv[15];
    u16* w2t = (u16*)alloc((size_t)1024 * 256 * 2);
    u16* w3t = (u16*)alloc((size_t)1024 * 1024 * 2);
    u16* g1t = (u16*)alloc((size_t)3 * 256 * 64 * 2);
    u16* g2t = (u16*)alloc((size_t)3 * 256 * 256 * 2);
    u16* g3t = (u16*)alloc((size_t)3 * 64 * 256 * 2);
    float* agg = (float*)alloc((size_t)NN * 64 * 4);   // doubles as x_cur (fp32)
    char* scratch = (char*)alloc(0);
    size_t avail = (ws_size > off + 4096) ? (ws_size - off - 4096) : 0;

    // ---- NNConv edge-chunk: h1c (512 B/e) + h2c (2048 B/e) + wec (2048 B/e) ----
    long CE = (long)(avail / 4608) & ~127L;
    if (CE < 128) CE = 128;
    if (CE > 200064) CE = 200064;
    u16* h1c = (u16*)scratch;
    u16* h2c = (u16*)(scratch + (size_t)CE * 512);
    u16* wec = (u16*)(scratch + (size_t)CE * 2560);

    // ---- GIN node-chunk: nbr+xin fixed (19.2MB) + 1152 B/node ----
    long gin_fixed = (long)NN * 64 * 4 + (long)NN * 64 * 2;
    long gin_avail = (long)avail - gin_fixed;
    if (gin_avail < 0) gin_avail = 0;
    long CN = (gin_avail / 1152) & ~127L;
    if (CN < 128) CN = 128;
    if (CN > 50048) CN = 50048;
    float* nbr = (float*)scratch;
    u16* xin   = (u16*)(scratch + (size_t)NN * 64 * 4);
    u16* hin   = (u16*)(scratch + gin_fixed);
    u16* hg1   = hin + (size_t)CN * 64;
    u16* hg2   = hg1 + (size_t)CN * 256;

    auto cdiv = [](long a, long b) { return (unsigned)((a + b - 1) / b); };

    // dtype probe on x, then normalize all float inputs to bf16
    hipMemsetAsync(cnt, 0, 4, stream);
    probe_f32<<<1, 256, 0, stream>>>((const u16*)d_in[0], cnt);
    for (int i = 0; i < 16; ++i)
        cvt_bf16<<<cdiv(cv_n[i], 256), 256, 0, stream>>>(d_in[cv_idx[i]], cv[i], cv_n[i], cnt);

    // edge_index conversion (layout-robust)
    hipMemsetAsync(flag, 0, 4, stream);
    detect_idx64<<<cdiv(EE, 256), 256, 0, stream>>>((const unsigned long long*)eidx, flag);
    convert_idx<<<cdiv(EE, 256), 256, 0, stream>>>(eidx, flag, src32, dst32);

    // weight transposes [K,N] -> [N,K]
    transpose_bf16<<<cdiv(256 * 1024, 256), 256, 0, stream>>>(w2c, w2t, 256, 1024);
    transpose_bf16<<<cdiv(1024 * 1024, 256), 256, 0, stream>>>(w3c, w3t, 1024, 1024);
    for (int l = 0; l < 3; ++l) {
        transpose_bf16<<<cdiv(64 * 256, 256), 256, 0, stream>>>(g1c + l * 64 * 256, g1t + l * 256 * 64, 64, 256);
        transpose_bf16<<<cdiv(256 * 256, 256), 256, 0, stream>>>(g2c + l * 256 * 256, g2t + l * 256 * 256, 256, 256);
        transpose_bf16<<<cdiv(256 * 64, 256), 256, 0, stream>>>(g3c + l * 256 * 64, g3t + l * 64 * 256, 256, 64);
    }

    // ---- NNConv (edge-chunked) ----
    hipMemsetAsync(agg, 0, (size_t)NN * 64 * 4, stream);
    for (long e0 = 0; e0 < EE; e0 += CE) {
        int ce = (int)((EE - e0 < CE) ? (EE - e0) : CE);
        edge_mlp1<<<cdiv(ce, 16), 256, 0, stream>>>(eac + e0 * 16, w1c, b1c, h1c, ce);
        gemm_bt_bias_elu<<<dim3(8, cdiv(ce, 128)), 256, 0, stream>>>(h1c, w2t, b2c, h2c, ce, 256, 1024);
        gemm_bt_bias_elu<<<dim3(8, cdiv(ce, 128)), 256, 0, stream>>>(h2c, w3t, b3c, wec, ce, 1024, 1024);
        nnconv_msg<<<cdiv((long)ce * 64, 256), 256, 0, stream>>>(wec, xc, src32 + e0, dst32 + e0, agg, ce);
    }
    add_root_out<<<cdiv((long)NN * 64, 256), 256, 0, stream>>>(xc, rwc, rbc, agg, out);

    // ---- 3x GINConv (node-chunked MLP) ----
    for (int l = 0; l < 3; ++l) {
        elu_bf16<<<cdiv((long)NN * 64, 256), 256, 0, stream>>>(agg, xin, (long)NN * 64);
        hipMemsetAsync(nbr, 0, (size_t)NN * 64 * 4, stream);
        gin_scatter<<<cdiv((long)EE * 64, 256), 256, 0, stream>>>(xin, src32, dst32, nbr);
        for (long n0 = 0; n0 < NN; n0 += CN) {
            int cn = (int)((NN - n0 < CN) ? (NN - n0) : CN);
            gin_combine<<<cdiv((long)cn * 64, 256), 256, 0, stream>>>(xin + n0 * 64, nbr + n0 * 64, hin, (long)cn * 64);
            gemm_bt_bias_elu<<<dim3(2, cdiv(cn, 128)), 256, 0, stream>>>(hin, g1t + l * 256 * 64, gb1c + l * 256, hg1, cn, 64, 256);
            gemm_bt_bias_elu<<<dim3(2, cdiv(cn, 128)), 256, 0, stream>>>(hg1, g2t + l * 256 * 256, gb2c + l * 256, hg2, cn, 256, 256);
            gin_out<<<cdiv((long)cn * 64, 256), 256, 0, stream>>>(hg2, g3t + l * 64 * 256, gb3c + l * 64, agg + n0 * 64, out + n0 * 256, l + 1, cn);
        }
    }
}

// Round 7
// 1729.103 us; speedup vs baseline: 1.3736x; 1.3736x over previous
//
#include <hip/hip_runtime.h>
#include <hip/hip_bf16.h>

// GraphEncoder: NNConv (edge-MLP 16->256->1024->1024 + einsum + scatter) + 3x GINConv.
// R6 PASSED (2375us). Counters: gin_out = 3x240us, MfmaUtil=0, WRITE 62.5MB vs 25.6MB
// payload (4x write amplification from stride-16B stores). R7:
//  (1) gin_out -> MFMA gemm_bt_f32 (256x64 tile) into contiguous fp32 emb[l];
//  (2) single coalesced float4 write_out at the end (out written once, full lines);
//  (3) global_load_lds staging re-enabled (R3==R4 bit-identical proved it correct).

#define NN 50000
#define EE 200000

typedef unsigned short u16;
typedef __attribute__((ext_vector_type(8))) short frag8;
typedef __attribute__((ext_vector_type(4))) float f32x4;

__device__ __forceinline__ float bf2f(u16 u) {
    union { unsigned int i; float f; } v; v.i = ((unsigned int)u) << 16; return v.f;
}
__device__ __forceinline__ u16 f2bf(float f) {
    union { float f; unsigned int i; } v; v.f = f;
    return (u16)((v.i + 0x7fffu + ((v.i >> 16) & 1u)) >> 16);
}
__device__ __forceinline__ float eluf(float v) {
    return v > 0.f ? v : __expf(v) - 1.f;
}

// ---------------- float dtype probe: fp32-as-bf16 shows crazy exponents ----------------
__global__ void probe_f32(const u16* __restrict__ raw, int* __restrict__ cnt) {
    int t = threadIdx.x;  // single block of 256
    int c = 0;
    for (int j = t; j < 1024; j += 256) {
        unsigned e = (raw[j] >> 7) & 0xFF;
        if (e >= 0xBF) c++;   // |v| >= 2^64: never in genuine N(0,1)-ish bf16 data
    }
    if (c) atomicAdd(cnt, c);
}
// dst bf16 <- src (fp32 if *cnt>=8 else bf16 passthrough)
__global__ void cvt_bf16(const void* __restrict__ src, u16* __restrict__ dst, long n,
                         const int* __restrict__ cnt) {
    long i = (long)blockIdx.x * 256 + threadIdx.x;
    if (i >= n) return;
    if (*cnt >= 8) dst[i] = f2bf(((const float*)src)[i]);
    else           dst[i] = ((const u16*)src)[i];
}

// ---------------- edge_index layout probe + conversion ----------------
__global__ void detect_idx64(const unsigned long long* __restrict__ p, int* __restrict__ flag) {
    long t = (long)blockIdx.x * 256 + threadIdx.x;
    if (t < EE) {
        unsigned long long v = p[t];
        if (v >> 31) atomicOr(flag, 1);   // int32-packed pairs have high bits set
    }
}
__global__ void convert_idx(const void* __restrict__ raw, const int* __restrict__ flag,
                            int* __restrict__ s_out, int* __restrict__ d_out) {
    long t = (long)blockIdx.x * 256 + threadIdx.x;
    if (t >= EE) return;
    if (*flag) {  // int32 layout
        const int* q = (const int*)raw;
        s_out[t] = q[t];
        d_out[t] = q[EE + t];
    } else {      // int64 layout
        const long long* q = (const long long*)raw;
        s_out[t] = (int)q[t];
        d_out[t] = (int)q[EE + t];
    }
}

// ---------------- generic bf16 transpose [K,N] -> [N,K] ----------------
__global__ void transpose_bf16(const u16* __restrict__ in, u16* __restrict__ out, int K, int N) {
    long idx = (long)blockIdx.x * 256 + threadIdx.x;
    if (idx < (long)K * N) {
        int k = (int)(idx / N);
        int n = (int)(idx % N);
        out[(long)n * K + k] = in[idx];
    }
}

// ---------------- edge MLP layer 1: h1 = ELU(attr @ W1 + b1), K=16, N=256 ----------------
__global__ void edge_mlp1(const u16* __restrict__ attr, const u16* __restrict__ w1,
                          const u16* __restrict__ b1, u16* __restrict__ h1, int ce) {
    __shared__ u16 sa[256];
    const int t = threadIdx.x;
    const int e0 = blockIdx.x * 16;
    const int cnt = min(16, ce - e0);
    sa[t] = (t < cnt * 16) ? attr[(long)e0 * 16 + t] : (u16)0;
    float w[16];
    #pragma unroll
    for (int i = 0; i < 16; ++i) w[i] = bf2f(w1[i * 256 + t]);
    const float bb = bf2f(b1[t]);
    __syncthreads();
    for (int e = 0; e < cnt; ++e) {
        float v = bb;
        #pragma unroll
        for (int i = 0; i < 16; ++i) v += bf2f(sa[e * 16 + i]) * w[i];
        h1[(long)(e0 + e) * 256 + t] = f2bf(eluf(v));
    }
}

// ---- stage 128x32 bf16 tile via global_load_lds (proven correct: R3==R4 bitwise) ----
__device__ __forceinline__ void stage_tile(const u16* g, long row_base, long max_row,
                                           int kstride, int k0, u16* s, int t) {
    int wave = t >> 6;
    #pragma unroll
    for (int j = 0; j < 2; ++j) {
        int c = t + 256 * j;                 // chunk id 0..511 (16B each)
        long r = row_base + (c >> 2);        // 4 chunks per 32-elem row
        if (r > max_row) r = max_row;        // tail clamp (masked at C store)
        const u16* gp = g + r * (long)kstride + k0 + (c & 3) * 8;
        __builtin_amdgcn_global_load_lds(
            (__attribute__((address_space(1))) void*)(void*)gp,
            (__attribute__((address_space(3))) void*)((char*)s + wave * 1024 + j * 4096),
            16, 0, 0);                       // HW writes LDS at base + lane*16
    }
}

// C = ELU(A[M,K] @ BT[N,K]^T + bias), bf16 out. N mult of 128, K mult of 32.
// blockIdx.x = N-tile (fast), blockIdx.y = M-tile -> consecutive blocks share A-tile.
__global__ __launch_bounds__(256)
void gemm_bt_bias_elu(const u16* __restrict__ A, const u16* __restrict__ BT,
                      const u16* __restrict__ bias, u16* __restrict__ C,
                      int M, int K, int N) {
    __shared__ __align__(16) u16 sA[128 * 32];
    __shared__ __align__(16) u16 sB[128 * 32];
    const int t = threadIdx.x;
    const int lane = t & 63;
    const int wave = t >> 6;
    const int wr = wave >> 1, wc = wave & 1;
    const int quad = lane >> 4, l16 = lane & 15;
    const long m0 = (long)blockIdx.y * 128;
    const int n0 = blockIdx.x * 128;

    f32x4 acc[4][4];
    const f32x4 z4 = {0.f, 0.f, 0.f, 0.f};
    #pragma unroll
    for (int mi = 0; mi < 4; ++mi)
        #pragma unroll
        for (int ni = 0; ni < 4; ++ni)
            acc[mi][ni] = z4;

    for (int k0 = 0; k0 < K; k0 += 32) {
        stage_tile(A, m0, (long)M - 1, K, k0, sA, t);
        stage_tile(BT, n0, (long)N - 1, K, k0, sB, t);
        __syncthreads();
        frag8 af[4], bfv[4];
        #pragma unroll
        for (int mi = 0; mi < 4; ++mi)
            af[mi] = *(const frag8*)(sA + (wr * 64 + mi * 16 + l16) * 32 + quad * 8);
        #pragma unroll
        for (int ni = 0; ni < 4; ++ni)
            bfv[ni] = *(const frag8*)(sB + (wc * 64 + ni * 16 + l16) * 32 + quad * 8);
        #pragma unroll
        for (int mi = 0; mi < 4; ++mi)
            #pragma unroll
            for (int ni = 0; ni < 4; ++ni)
                acc[mi][ni] = __builtin_amdgcn_mfma_f32_16x16x32_bf16(af[mi], bfv[ni], acc[mi][ni], 0, 0, 0);
        __syncthreads();
    }

    #pragma unroll
    for (int mi = 0; mi < 4; ++mi) {
        #pragma unroll
        for (int r = 0; r < 4; ++r) {
            long row = m0 + wr * 64 + mi * 16 + quad * 4 + r;  // C/D: row = quad*4+reg
            if (row < M) {
                #pragma unroll
                for (int ni = 0; ni < 4; ++ni) {
                    int col = n0 + wc * 64 + ni * 16 + l16;    // C/D: col = lane&15
                    float v = acc[mi][ni][r] + bf2f(bias[col]);
                    C[row * (long)N + col] = f2bf(eluf(v));
                }
            }
        }
    }
}

// C[M,64] fp32 = A[M,K] @ BT[64,K]^T + bias (no ELU). M-tile 256, N=64, K mult of 32.
__global__ __launch_bounds__(256)
void gemm_bt_f32(const u16* __restrict__ A, const u16* __restrict__ BT,
                 const u16* __restrict__ bias, float* __restrict__ C,
                 int M, int K) {
    __shared__ __align__(16) u16 sA[256 * 32];
    __shared__ __align__(16) u16 sB[64 * 32];
    const int t = threadIdx.x;
    const int lane = t & 63;
    const int wave = t >> 6;
    const int quad = lane >> 4, l16 = lane & 15;
    const long m0 = (long)blockIdx.x * 256;

    f32x4 acc[4][4];
    const f32x4 z4 = {0.f, 0.f, 0.f, 0.f};
    #pragma unroll
    for (int mi = 0; mi < 4; ++mi)
        #pragma unroll
        for (int ni = 0; ni < 4; ++ni)
            acc[mi][ni] = z4;

    for (int k0 = 0; k0 < K; k0 += 32) {
        // A: 256x32 = 1024 chunks of 16B; thread t stages chunks t+256j, j=0..3
        #pragma unroll
        for (int j = 0; j < 4; ++j) {
            int c = t + 256 * j;
            long r = m0 + (c >> 2);
            if (r > (long)M - 1) r = (long)M - 1;
            const u16* gp = A + r * (long)K + k0 + (c & 3) * 8;
            __builtin_amdgcn_global_load_lds(
                (__attribute__((address_space(1))) void*)(void*)gp,
                (__attribute__((address_space(3))) void*)((char*)sA + wave * 1024 + j * 4096),
                16, 0, 0);
        }
        // B: 64x32 = 256 chunks; thread t stages chunk t
        {
            int c = t;
            const u16* gp = BT + (long)(c >> 2) * K + k0 + (c & 3) * 8;
            __builtin_amdgcn_global_load_lds(
                (__attribute__((address_space(1))) void*)(void*)gp,
                (__attribute__((address_space(3))) void*)((char*)sB + wave * 1024),
                16, 0, 0);
        }
        __syncthreads();
        frag8 af[4], bfv[4];
        #pragma unroll
        for (int mi = 0; mi < 4; ++mi)
            af[mi] = *(const frag8*)(sA + (wave * 64 + mi * 16 + l16) * 32 + quad * 8);
        #pragma unroll
        for (int ni = 0; ni < 4; ++ni)
            bfv[ni] = *(const frag8*)(sB + (ni * 16 + l16) * 32 + quad * 8);
        #pragma unroll
        for (int mi = 0; mi < 4; ++mi)
            #pragma unroll
            for (int ni = 0; ni < 4; ++ni)
                acc[mi][ni] = __builtin_amdgcn_mfma_f32_16x16x32_bf16(af[mi], bfv[ni], acc[mi][ni], 0, 0, 0);
        __syncthreads();
    }

    #pragma unroll
    for (int mi = 0; mi < 4; ++mi) {
        #pragma unroll
        for (int r = 0; r < 4; ++r) {
            long row = m0 + wave * 64 + mi * 16 + quad * 4 + r;
            if (row < M) {
                #pragma unroll
                for (int ni = 0; ni < 4; ++ni) {
                    int col = ni * 16 + l16;
                    C[row * 64 + col] = acc[mi][ni][r] + bf2f(bias[col]);
                }
            }
        }
    }
}

// msg[e,o] = sum_i x[src[e],i] * we[e, i*64+o]; atomicAdd into agg[dst[e],o]
__global__ void nnconv_msg(const u16* __restrict__ we, const u16* __restrict__ x,
                           const int* __restrict__ src, const int* __restrict__ dst,
                           float* __restrict__ agg, int ce) {
    long idx = (long)blockIdx.x * 256 + threadIdx.x;
    if (idx >= (long)ce * 64) return;
    int o = (int)(idx & 63);
    long e = idx >> 6;
    const u16* wr = we + e * 1024;
    const u16* xr = x + (long)src[e] * 16;
    float v = 0.f;
    #pragma unroll
    for (int i = 0; i < 16; ++i)
        v += bf2f(xr[i]) * bf2f(wr[i * 64 + o]);
    atomicAdd(&agg[(long)dst[e] * 64 + o], v);
}

// ---- x_cur(emb0) = x @ root_w + root_b + agg (in-place on agg) ----
__global__ void add_root(const u16* __restrict__ x, const u16* __restrict__ rw,
                         const u16* __restrict__ rb, float* __restrict__ xcur) {
    long idx = (long)blockIdx.x * 256 + threadIdx.x;
    if (idx >= (long)NN * 64) return;
    int d = (int)(idx & 63);
    long n = idx >> 6;
    float v = bf2f(rb[d]);
    #pragma unroll
    for (int i = 0; i < 16; ++i)
        v += bf2f(x[n * 16 + i]) * bf2f(rw[i * 64 + d]);
    xcur[idx] += v;
}

__global__ void elu_bf16(const float* __restrict__ in, u16* __restrict__ o, long n) {
    long idx = (long)blockIdx.x * 256 + threadIdx.x;
    if (idx < n) o[idx] = f2bf(eluf(in[idx]));
}

__global__ void gin_scatter(const u16* __restrict__ xin, const int* __restrict__ src,
                            const int* __restrict__ dst, float* __restrict__ nbr) {
    long idx = (long)blockIdx.x * 256 + threadIdx.x;
    if (idx >= (long)EE * 64) return;
    int d = (int)(idx & 63);
    long e = idx >> 6;
    atomicAdd(&nbr[(long)dst[e] * 64 + d], bf2f(xin[(long)src[e] * 64 + d]));
}

__global__ void gin_combine(const u16* __restrict__ xin, const float* __restrict__ nbr,
                            u16* __restrict__ hin, long n) {
    long idx = (long)blockIdx.x * 256 + threadIdx.x;
    if (idx < n) hin[idx] = f2bf(bf2f(xin[idx]) + nbr[idx]);
}

// out[n,d,l] = emb_l[n*64+d] -- one float4 per (n,d), fully coalesced
__global__ void write_out(const float* __restrict__ e0, const float* __restrict__ e1,
                          const float* __restrict__ e2, const float* __restrict__ e3,
                          float* __restrict__ out) {
    long idx = (long)blockIdx.x * 256 + threadIdx.x;
    if (idx >= (long)NN * 64) return;
    float4 v = {e0[idx], e1[idx], e2[idx], e3[idx]};
    *(float4*)(out + idx * 4) = v;
}

extern "C" void kernel_launch(void* const* d_in, const int* in_sizes, int n_in,
                              void* d_out, int out_size, void* d_ws, size_t ws_size,
                              hipStream_t stream) {
    (void)in_sizes; (void)n_in; (void)out_size;
    const void* eidx = d_in[1];
    float* out = (float*)d_out;   // reference output dtype = float32

    char* ws = (char*)d_ws;
    size_t off = 0;
    auto alloc = [&](size_t bytes) {
        char* p = ws + off;
        off += (bytes + 255) & ~(size_t)255;
        return p;
    };
    // ---- persistent ----
    int* src32 = (int*)alloc((size_t)EE * 4);
    int* dst32 = (int*)alloc((size_t)EE * 4);
    int* flag  = (int*)alloc(256);
    int* cnt   = (int*)alloc(256);
    const int cv_idx[16] = {0, 2, 3, 4, 5, 6, 7, 8, 9, 10, 11, 12, 13, 14, 15, 16};
    const long cv_n[16]  = {800000, 3200000, 4096, 256, 262144, 1024, 1048576, 1024,
                            1024, 64, 49152, 768, 196608, 768, 49152, 192};
    u16* cv[16];
    for (int i = 0; i < 16; ++i) cv[i] = (u16*)alloc((size_t)cv_n[i] * 2);
    u16 *xc = cv[0], *eac = cv[1], *w1c = cv[2], *b1c = cv[3], *w2c = cv[4], *b2c = cv[5],
        *w3c = cv[6], *b3c = cv[7], *rwc = cv[8], *rbc = cv[9],
        *g1c = cv[10], *gb1c = cv[11], *g2c = cv[12], *gb2c = cv[13], *g3c = cv[14], *gb3c = cv[15];
    u16* w2t = (u16*)alloc((size_t)1024 * 256 * 2);
    u16* w3t = (u16*)alloc((size_t)1024 * 1024 * 2);
    u16* g1t = (u16*)alloc((size_t)3 * 256 * 64 * 2);
    u16* g2t = (u16*)alloc((size_t)3 * 256 * 256 * 2);
    u16* g3t = (u16*)alloc((size_t)3 * 64 * 256 * 2);
    // per-layer node embeddings, fp32 [N,64]; emb[0] doubles as agg/x_cur
    float* emb[4];
    for (int l = 0; l < 4; ++l) emb[l] = (float*)alloc((size_t)NN * 64 * 4);
    float* agg = emb[0];
    char* scratch = (char*)alloc(0);
    size_t avail = (ws_size > off + 4096) ? (ws_size - off - 4096) : 0;

    // ---- NNConv edge-chunk: h1c (512 B/e) + h2c (2048 B/e) + wec (2048 B/e) ----
    long CE = (long)(avail / 4608) & ~127L;
    if (CE < 128) CE = 128;
    if (CE > 200064) CE = 200064;
    u16* h1c = (u16*)scratch;
    u16* h2c = (u16*)(scratch + (size_t)CE * 512);
    u16* wec = (u16*)(scratch + (size_t)CE * 2560);

    // ---- GIN node-chunk: nbr+xin fixed (19.2MB) + 1152 B/node ----
    long gin_fixed = (long)NN * 64 * 4 + (long)NN * 64 * 2;
    long gin_avail = (long)avail - gin_fixed;
    if (gin_avail < 0) gin_avail = 0;
    long CN = (gin_avail / 1152) & ~255L;
    if (CN < 256) CN = 256;
    if (CN > 50176) CN = 50176;
    float* nbr = (float*)scratch;
    u16* xin   = (u16*)(scratch + (size_t)NN * 64 * 4);
    u16* hin   = (u16*)(scratch + gin_fixed);
    u16* hg1   = hin + (size_t)CN * 64;
    u16* hg2   = hg1 + (size_t)CN * 256;

    auto cdiv = [](long a, long b) { return (unsigned)((a + b - 1) / b); };

    // dtype probe on x, then normalize all float inputs to bf16
    hipMemsetAsync(cnt, 0, 4, stream);
    probe_f32<<<1, 256, 0, stream>>>((const u16*)d_in[0], cnt);
    for (int i = 0; i < 16; ++i)
        cvt_bf16<<<cdiv(cv_n[i], 256), 256, 0, stream>>>(d_in[cv_idx[i]], cv[i], cv_n[i], cnt);

    // edge_index conversion (layout-robust)
    hipMemsetAsync(flag, 0, 4, stream);
    detect_idx64<<<cdiv(EE, 256), 256, 0, stream>>>((const unsigned long long*)eidx, flag);
    convert_idx<<<cdiv(EE, 256), 256, 0, stream>>>(eidx, flag, src32, dst32);

    // weight transposes [K,N] -> [N,K]
    transpose_bf16<<<cdiv(256 * 1024, 256), 256, 0, stream>>>(w2c, w2t, 256, 1024);
    transpose_bf16<<<cdiv(1024 * 1024, 256), 256, 0, stream>>>(w3c, w3t, 1024, 1024);
    for (int l = 0; l < 3; ++l) {
        transpose_bf16<<<cdiv(64 * 256, 256), 256, 0, stream>>>(g1c + l * 64 * 256, g1t + l * 256 * 64, 64, 256);
        transpose_bf16<<<cdiv(256 * 256, 256), 256, 0, stream>>>(g2c + l * 256 * 256, g2t + l * 256 * 256, 256, 256);
        transpose_bf16<<<cdiv(256 * 64, 256), 256, 0, stream>>>(g3c + l * 256 * 64, g3t + l * 64 * 256, 256, 64);
    }

    // ---- NNConv (edge-chunked) ----
    hipMemsetAsync(agg, 0, (size_t)NN * 64 * 4, stream);
    for (long e0 = 0; e0 < EE; e0 += CE) {
        int ce = (int)((EE - e0 < CE) ? (EE - e0) : CE);
        edge_mlp1<<<cdiv(ce, 16), 256, 0, stream>>>(eac + e0 * 16, w1c, b1c, h1c, ce);
        gemm_bt_bias_elu<<<dim3(8, cdiv(ce, 128)), 256, 0, stream>>>(h1c, w2t, b2c, h2c, ce, 256, 1024);
        gemm_bt_bias_elu<<<dim3(8, cdiv(ce, 128)), 256, 0, stream>>>(h2c, w3t, b3c, wec, ce, 1024, 1024);
        nnconv_msg<<<cdiv((long)ce * 64, 256), 256, 0, stream>>>(wec, xc, src32 + e0, dst32 + e0, agg, ce);
    }
    add_root<<<cdiv((long)NN * 64, 256), 256, 0, stream>>>(xc, rwc, rbc, agg);

    // ---- 3x GINConv (node-chunked MLP) ----
    for (int l = 0; l < 3; ++l) {
        elu_bf16<<<cdiv((long)NN * 64, 256), 256, 0, stream>>>(emb[l], xin, (long)NN * 64);
        hipMemsetAsync(nbr, 0, (size_t)NN * 64 * 4, stream);
        gin_scatter<<<cdiv((long)EE * 64, 256), 256, 0, stream>>>(xin, src32, dst32, nbr);
        for (long n0 = 0; n0 < NN; n0 += CN) {
            int cn = (int)((NN - n0 < CN) ? (NN - n0) : CN);
            gin_combine<<<cdiv((long)cn * 64, 256), 256, 0, stream>>>(xin + n0 * 64, nbr + n0 * 64, hin, (long)cn * 64);
            gemm_bt_bias_elu<<<dim3(2, cdiv(cn, 128)), 256, 0, stream>>>(hin, g1t + l * 256 * 64, gb1c + l * 256, hg1, cn, 64, 256);
            gemm_bt_bias_elu<<<dim3(2, cdiv(cn, 128)), 256, 0, stream>>>(hg1, g2t + l * 256 * 256, gb2c + l * 256, hg2, cn, 256, 256);
            gemm_bt_f32<<<cdiv(cn, 256), 256, 0, stream>>>(hg2, g3t + l * 64 * 256, gb3c + l * 64, emb[l + 1] + n0 * 64, cn, 256);
        }
    }
    write_out<<<cdiv((long)NN * 64, 256), 256, 0, stream>>>(emb[0], emb[1], emb[2], emb[3], out);
}

// Round 8
// 1629.326 us; speedup vs baseline: 1.4577x; 1.0612x over previous
//
#include <hip/hip_runtime.h>
#include <hip/hip_bf16.h>

// GraphEncoder: NNConv (edge-MLP 16->256->1024->1024 + einsum + scatter) + 3x GINConv.
// R7: 1729us. Top-5 = enn-L3 gemm chunks: FETCH 353MB vs A=89MB -> A fetched 3.95x
// because n-tile-fast grid spreads the 8 blocks sharing an A-tile across 8 XCDs
// (private L2s each refetch). R8: XCD-aware swizzle -- 1D grid, xcd=bid&7 owns an
// M-slab, n-tiles of one m temporally adjacent on one XCD (256KB tile << 4MB L2).
// Applies to gemm_bt_bias_elu (enn-L2, enn-L3, GIN g1/g2). Everything else = R7.

#define NN 50000
#define EE 200000

typedef unsigned short u16;
typedef __attribute__((ext_vector_type(8))) short frag8;
typedef __attribute__((ext_vector_type(4))) float f32x4;

__device__ __forceinline__ float bf2f(u16 u) {
    union { unsigned int i; float f; } v; v.i = ((unsigned int)u) << 16; return v.f;
}
__device__ __forceinline__ u16 f2bf(float f) {
    union { float f; unsigned int i; } v; v.f = f;
    return (u16)((v.i + 0x7fffu + ((v.i >> 16) & 1u)) >> 16);
}
__device__ __forceinline__ float eluf(float v) {
    return v > 0.f ? v : __expf(v) - 1.f;
}

// ---------------- float dtype probe: fp32-as-bf16 shows crazy exponents ----------------
__global__ void probe_f32(const u16* __restrict__ raw, int* __restrict__ cnt) {
    int t = threadIdx.x;  // single block of 256
    int c = 0;
    for (int j = t; j < 1024; j += 256) {
        unsigned e = (raw[j] >> 7) & 0xFF;
        if (e >= 0xBF) c++;   // |v| >= 2^64: never in genuine N(0,1)-ish bf16 data
    }
    if (c) atomicAdd(cnt, c);
}
// dst bf16 <- src (fp32 if *cnt>=8 else bf16 passthrough)
__global__ void cvt_bf16(const void* __restrict__ src, u16* __restrict__ dst, long n,
                         const int* __restrict__ cnt) {
    long i = (long)blockIdx.x * 256 + threadIdx.x;
    if (i >= n) return;
    if (*cnt >= 8) dst[i] = f2bf(((const float*)src)[i]);
    else           dst[i] = ((const u16*)src)[i];
}

// ---------------- edge_index layout probe + conversion ----------------
__global__ void detect_idx64(const unsigned long long* __restrict__ p, int* __restrict__ flag) {
    long t = (long)blockIdx.x * 256 + threadIdx.x;
    if (t < EE) {
        unsigned long long v = p[t];
        if (v >> 31) atomicOr(flag, 1);   // int32-packed pairs have high bits set
    }
}
__global__ void convert_idx(const void* __restrict__ raw, const int* __restrict__ flag,
                            int* __restrict__ s_out, int* __restrict__ d_out) {
    long t = (long)blockIdx.x * 256 + threadIdx.x;
    if (t >= EE) return;
    if (*flag) {  // int32 layout
        const int* q = (const int*)raw;
        s_out[t] = q[t];
        d_out[t] = q[EE + t];
    } else {      // int64 layout
        const long long* q = (const long long*)raw;
        s_out[t] = (int)q[t];
        d_out[t] = (int)q[EE + t];
    }
}

// ---------------- generic bf16 transpose [K,N] -> [N,K] ----------------
__global__ void transpose_bf16(const u16* __restrict__ in, u16* __restrict__ out, int K, int N) {
    long idx = (long)blockIdx.x * 256 + threadIdx.x;
    if (idx < (long)K * N) {
        int k = (int)(idx / N);
        int n = (int)(idx % N);
        out[(long)n * K + k] = in[idx];
    }
}

// ---------------- edge MLP layer 1: h1 = ELU(attr @ W1 + b1), K=16, N=256 ----------------
__global__ void edge_mlp1(const u16* __restrict__ attr, const u16* __restrict__ w1,
                          const u16* __restrict__ b1, u16* __restrict__ h1, int ce) {
    __shared__ u16 sa[256];
    const int t = threadIdx.x;
    const int e0 = blockIdx.x * 16;
    const int cnt = min(16, ce - e0);
    sa[t] = (t < cnt * 16) ? attr[(long)e0 * 16 + t] : (u16)0;
    float w[16];
    #pragma unroll
    for (int i = 0; i < 16; ++i) w[i] = bf2f(w1[i * 256 + t]);
    const float bb = bf2f(b1[t]);
    __syncthreads();
    for (int e = 0; e < cnt; ++e) {
        float v = bb;
        #pragma unroll
        for (int i = 0; i < 16; ++i) v += bf2f(sa[e * 16 + i]) * w[i];
        h1[(long)(e0 + e) * 256 + t] = f2bf(eluf(v));
    }
}

// ---- stage 128x32 bf16 tile via global_load_lds ----
__device__ __forceinline__ void stage_tile(const u16* g, long row_base, long max_row,
                                           int kstride, int k0, u16* s, int t) {
    int wave = t >> 6;
    #pragma unroll
    for (int j = 0; j < 2; ++j) {
        int c = t + 256 * j;                 // chunk id 0..511 (16B each)
        long r = row_base + (c >> 2);        // 4 chunks per 32-elem row
        if (r > max_row) r = max_row;        // tail clamp (masked at C store)
        const u16* gp = g + r * (long)kstride + k0 + (c & 3) * 8;
        __builtin_amdgcn_global_load_lds(
            (__attribute__((address_space(1))) void*)(void*)gp,
            (__attribute__((address_space(3))) void*)((char*)s + wave * 1024 + j * 4096),
            16, 0, 0);                       // HW writes LDS at base + lane*16
    }
}

// C = ELU(A[M,K] @ BT[N,K]^T + bias), bf16 out. N mult of 128, K mult of 32.
// XCD-swizzled 1D grid (8*mpx*nt blocks): xcd=bid&7 owns M-slab [xcd*mpx, ...);
// its blocks iterate n fast -> each A-tile fetched by exactly one XCD's L2.
__global__ __launch_bounds__(256)
void gemm_bt_bias_elu(const u16* __restrict__ A, const u16* __restrict__ BT,
                      const u16* __restrict__ bias, u16* __restrict__ C,
                      int M, int K, int N, int mpx, int lognt) {
    const int bid = blockIdx.x;
    const int xcd = bid & 7;
    const int j = bid >> 3;
    const int m_idx = xcd * mpx + (j >> lognt);
    const int n_idx = j & ((1 << lognt) - 1);
    const int num_m = (M + 127) >> 7;
    if (m_idx >= num_m) return;              // block-uniform; before any barrier

    __shared__ __align__(16) u16 sA[128 * 32];
    __shared__ __align__(16) u16 sB[128 * 32];
    const int t = threadIdx.x;
    const int lane = t & 63;
    const int wave = t >> 6;
    const int wr = wave >> 1, wc = wave & 1;
    const int quad = lane >> 4, l16 = lane & 15;
    const long m0 = (long)m_idx * 128;
    const int n0 = n_idx * 128;

    f32x4 acc[4][4];
    const f32x4 z4 = {0.f, 0.f, 0.f, 0.f};
    #pragma unroll
    for (int mi = 0; mi < 4; ++mi)
        #pragma unroll
        for (int ni = 0; ni < 4; ++ni)
            acc[mi][ni] = z4;

    for (int k0 = 0; k0 < K; k0 += 32) {
        stage_tile(A, m0, (long)M - 1, K, k0, sA, t);
        stage_tile(BT, n0, (long)N - 1, K, k0, sB, t);
        __syncthreads();
        frag8 af[4], bfv[4];
        #pragma unroll
        for (int mi = 0; mi < 4; ++mi)
            af[mi] = *(const frag8*)(sA + (wr * 64 + mi * 16 + l16) * 32 + quad * 8);
        #pragma unroll
        for (int ni = 0; ni < 4; ++ni)
            bfv[ni] = *(const frag8*)(sB + (wc * 64 + ni * 16 + l16) * 32 + quad * 8);
        #pragma unroll
        for (int mi = 0; mi < 4; ++mi)
            #pragma unroll
            for (int ni = 0; ni < 4; ++ni)
                acc[mi][ni] = __builtin_amdgcn_mfma_f32_16x16x32_bf16(af[mi], bfv[ni], acc[mi][ni], 0, 0, 0);
        __syncthreads();
    }

    #pragma unroll
    for (int mi = 0; mi < 4; ++mi) {
        #pragma unroll
        for (int r = 0; r < 4; ++r) {
            long row = m0 + wr * 64 + mi * 16 + quad * 4 + r;  // C/D: row = quad*4+reg
            if (row < M) {
                #pragma unroll
                for (int ni = 0; ni < 4; ++ni) {
                    int col = n0 + wc * 64 + ni * 16 + l16;    // C/D: col = lane&15
                    float v = acc[mi][ni][r] + bf2f(bias[col]);
                    C[row * (long)N + col] = f2bf(eluf(v));
                }
            }
        }
    }
}

// C[M,64] fp32 = A[M,K] @ BT[64,K]^T + bias (no ELU). M-tile 256, N=64, K mult of 32.
__global__ __launch_bounds__(256)
void gemm_bt_f32(const u16* __restrict__ A, const u16* __restrict__ BT,
                 const u16* __restrict__ bias, float* __restrict__ C,
                 int M, int K) {
    __shared__ __align__(16) u16 sA[256 * 32];
    __shared__ __align__(16) u16 sB[64 * 32];
    const int t = threadIdx.x;
    const int lane = t & 63;
    const int wave = t >> 6;
    const int quad = lane >> 4, l16 = lane & 15;
    const long m0 = (long)blockIdx.x * 256;

    f32x4 acc[4][4];
    const f32x4 z4 = {0.f, 0.f, 0.f, 0.f};
    #pragma unroll
    for (int mi = 0; mi < 4; ++mi)
        #pragma unroll
        for (int ni = 0; ni < 4; ++ni)
            acc[mi][ni] = z4;

    for (int k0 = 0; k0 < K; k0 += 32) {
        #pragma unroll
        for (int j = 0; j < 4; ++j) {
            int c = t + 256 * j;
            long r = m0 + (c >> 2);
            if (r > (long)M - 1) r = (long)M - 1;
            const u16* gp = A + r * (long)K + k0 + (c & 3) * 8;
            __builtin_amdgcn_global_load_lds(
                (__attribute__((address_space(1))) void*)(void*)gp,
                (__attribute__((address_space(3))) void*)((char*)sA + wave * 1024 + j * 4096),
                16, 0, 0);
        }
        {
            int c = t;
            const u16* gp = BT + (long)(c >> 2) * K + k0 + (c & 3) * 8;
            __builtin_amdgcn_global_load_lds(
                (__attribute__((address_space(1))) void*)(void*)gp,
                (__attribute__((address_space(3))) void*)((char*)sB + wave * 1024),
                16, 0, 0);
        }
        __syncthreads();
        frag8 af[4], bfv[4];
        #pragma unroll
        for (int mi = 0; mi < 4; ++mi)
            af[mi] = *(const frag8*)(sA + (wave * 64 + mi * 16 + l16) * 32 + quad * 8);
        #pragma unroll
        for (int ni = 0; ni < 4; ++ni)
            bfv[ni] = *(const frag8*)(sB + (ni * 16 + l16) * 32 + quad * 8);
        #pragma unroll
        for (int mi = 0; mi < 4; ++mi)
            #pragma unroll
            for (int ni = 0; ni < 4; ++ni)
                acc[mi][ni] = __builtin_amdgcn_mfma_f32_16x16x32_bf16(af[mi], bfv[ni], acc[mi][ni], 0, 0, 0);
        __syncthreads();
    }

    #pragma unroll
    for (int mi = 0; mi < 4; ++mi) {
        #pragma unroll
        for (int r = 0; r < 4; ++r) {
            long row = m0 + wave * 64 + mi * 16 + quad * 4 + r;
            if (row < M) {
                #pragma unroll
                for (int ni = 0; ni < 4; ++ni) {
                    int col = ni * 16 + l16;
                    C[row * 64 + col] = acc[mi][ni][r] + bf2f(bias[col]);
                }
            }
        }
    }
}

// msg[e,o] = sum_i x[src[e],i] * we[e, i*64+o]; atomicAdd into agg[dst[e],o]
__global__ void nnconv_msg(const u16* __restrict__ we, const u16* __restrict__ x,
                           const int* __restrict__ src, const int* __restrict__ dst,
                           float* __restrict__ agg, int ce) {
    long idx = (long)blockIdx.x * 256 + threadIdx.x;
    if (idx >= (long)ce * 64) return;
    int o = (int)(idx & 63);
    long e = idx >> 6;
    const u16* wr = we + e * 1024;
    const u16* xr = x + (long)src[e] * 16;
    float v = 0.f;
    #pragma unroll
    for (int i = 0; i < 16; ++i)
        v += bf2f(xr[i]) * bf2f(wr[i * 64 + o]);
    atomicAdd(&agg[(long)dst[e] * 64 + o], v);
}

// ---- x_cur(emb0) = x @ root_w + root_b + agg (in-place on agg) ----
__global__ void add_root(const u16* __restrict__ x, const u16* __restrict__ rw,
                         const u16* __restrict__ rb, float* __restrict__ xcur) {
    long idx = (long)blockIdx.x * 256 + threadIdx.x;
    if (idx >= (long)NN * 64) return;
    int d = (int)(idx & 63);
    long n = idx >> 6;
    float v = bf2f(rb[d]);
    #pragma unroll
    for (int i = 0; i < 16; ++i)
        v += bf2f(x[n * 16 + i]) * bf2f(rw[i * 64 + d]);
    xcur[idx] += v;
}

__global__ void elu_bf16(const float* __restrict__ in, u16* __restrict__ o, long n) {
    long idx = (long)blockIdx.x * 256 + threadIdx.x;
    if (idx < n) o[idx] = f2bf(eluf(in[idx]));
}

__global__ void gin_scatter(const u16* __restrict__ xin, const int* __restrict__ src,
                            const int* __restrict__ dst, float* __restrict__ nbr) {
    long idx = (long)blockIdx.x * 256 + threadIdx.x;
    if (idx >= (long)EE * 64) return;
    int d = (int)(idx & 63);
    long e = idx >> 6;
    atomicAdd(&nbr[(long)dst[e] * 64 + d], bf2f(xin[(long)src[e] * 64 + d]));
}

__global__ void gin_combine(const u16* __restrict__ xin, const float* __restrict__ nbr,
                            u16* __restrict__ hin, long n) {
    long idx = (long)blockIdx.x * 256 + threadIdx.x;
    if (idx < n) hin[idx] = f2bf(bf2f(xin[idx]) + nbr[idx]);
}

// out[n,d,l] = emb_l[n*64+d] -- one float4 per (n,d), fully coalesced
__global__ void write_out(const float* __restrict__ e0, const float* __restrict__ e1,
                          const float* __restrict__ e2, const float* __restrict__ e3,
                          float* __restrict__ out) {
    long idx = (long)blockIdx.x * 256 + threadIdx.x;
    if (idx >= (long)NN * 64) return;
    float4 v = {e0[idx], e1[idx], e2[idx], e3[idx]};
    *(float4*)(out + idx * 4) = v;
}

extern "C" void kernel_launch(void* const* d_in, const int* in_sizes, int n_in,
                              void* d_out, int out_size, void* d_ws, size_t ws_size,
                              hipStream_t stream) {
    (void)in_sizes; (void)n_in; (void)out_size;
    const void* eidx = d_in[1];
    float* out = (float*)d_out;   // reference output dtype = float32

    char* ws = (char*)d_ws;
    size_t off = 0;
    auto alloc = [&](size_t bytes) {
        char* p = ws + off;
        off += (bytes + 255) & ~(size_t)255;
        return p;
    };
    // ---- persistent ----
    int* src32 = (int*)alloc((size_t)EE * 4);
    int* dst32 = (int*)alloc((size_t)EE * 4);
    int* flag  = (int*)alloc(256);
    int* cnt   = (int*)alloc(256);
    const int cv_idx[16] = {0, 2, 3, 4, 5, 6, 7, 8, 9, 10, 11, 12, 13, 14, 15, 16};
    const long cv_n[16]  = {800000, 3200000, 4096, 256, 262144, 1024, 1048576, 1024,
                            1024, 64, 49152, 768, 196608, 768, 49152, 192};
    u16* cv[16];
    for (int i = 0; i < 16; ++i) cv[i] = (u16*)alloc((size_t)cv_n[i] * 2);
    u16 *xc = cv[0], *eac = cv[1], *w1c = cv[2], *b1c = cv[3], *w2c = cv[4], *b2c = cv[5],
        *w3c = cv[6], *b3c = cv[7], *rwc = cv[8], *rbc = cv[9],
        *g1c = cv[10], *gb1c = cv[11], *g2c = cv[12], *gb2c = cv[13], *g3c = cv[14], *gb3c = cv[15];
    u16* w2t = (u16*)alloc((size_t)1024 * 256 * 2);
    u16* w3t = (u16*)alloc((size_t)1024 * 1024 * 2);
    u16* g1t = (u16*)alloc((size_t)3 * 256 * 64 * 2);
    u16* g2t = (u16*)alloc((size_t)3 * 256 * 256 * 2);
    u16* g3t = (u16*)alloc((size_t)3 * 64 * 256 * 2);
    // per-layer node embeddings, fp32 [N,64]; emb[0] doubles as agg/x_cur
    float* emb[4];
    for (int l = 0; l < 4; ++l) emb[l] = (float*)alloc((size_t)NN * 64 * 4);
    float* agg = emb[0];
    char* scratch = (char*)alloc(0);
    size_t avail = (ws_size > off + 4096) ? (ws_size - off - 4096) : 0;

    // ---- NNConv edge-chunk: h1c (512 B/e) + h2c (2048 B/e) + wec (2048 B/e) ----
    long CE = (long)(avail / 4608) & ~127L;
    if (CE < 128) CE = 128;
    if (CE > 200064) CE = 200064;
    u16* h1c = (u16*)scratch;
    u16* h2c = (u16*)(scratch + (size_t)CE * 512);
    u16* wec = (u16*)(scratch + (size_t)CE * 2560);

    // ---- GIN node-chunk: nbr+xin fixed (19.2MB) + 1152 B/node ----
    long gin_fixed = (long)NN * 64 * 4 + (long)NN * 64 * 2;
    long gin_avail = (long)avail - gin_fixed;
    if (gin_avail < 0) gin_avail = 0;
    long CN = (gin_avail / 1152) & ~255L;
    if (CN < 256) CN = 256;
    if (CN > 50176) CN = 50176;
    float* nbr = (float*)scratch;
    u16* xin   = (u16*)(scratch + (size_t)NN * 64 * 4);
    u16* hin   = (u16*)(scratch + gin_fixed);
    u16* hg1   = hin + (size_t)CN * 64;
    u16* hg2   = hg1 + (size_t)CN * 256;

    auto cdiv = [](long a, long b) { return (unsigned)((a + b - 1) / b); };

    // dtype probe on x, then normalize all float inputs to bf16
    hipMemsetAsync(cnt, 0, 4, stream);
    probe_f32<<<1, 256, 0, stream>>>((const u16*)d_in[0], cnt);
    for (int i = 0; i < 16; ++i)
        cvt_bf16<<<cdiv(cv_n[i], 256), 256, 0, stream>>>(d_in[cv_idx[i]], cv[i], cv_n[i], cnt);

    // edge_index conversion (layout-robust)
    hipMemsetAsync(flag, 0, 4, stream);
    detect_idx64<<<cdiv(EE, 256), 256, 0, stream>>>((const unsigned long long*)eidx, flag);
    convert_idx<<<cdiv(EE, 256), 256, 0, stream>>>(eidx, flag, src32, dst32);

    // weight transposes [K,N] -> [N,K]
    transpose_bf16<<<cdiv(256 * 1024, 256), 256, 0, stream>>>(w2c, w2t, 256, 1024);
    transpose_bf16<<<cdiv(1024 * 1024, 256), 256, 0, stream>>>(w3c, w3t, 1024, 1024);
    for (int l = 0; l < 3; ++l) {
        transpose_bf16<<<cdiv(64 * 256, 256), 256, 0, stream>>>(g1c + l * 64 * 256, g1t + l * 256 * 64, 64, 256);
        transpose_bf16<<<cdiv(256 * 256, 256), 256, 0, stream>>>(g2c + l * 256 * 256, g2t + l * 256 * 256, 256, 256);
        transpose_bf16<<<cdiv(256 * 64, 256), 256, 0, stream>>>(g3c + l * 256 * 64, g3t + l * 64 * 256, 256, 64);
    }

    // ---- NNConv (edge-chunked) ----
    hipMemsetAsync(agg, 0, (size_t)NN * 64 * 4, stream);
    for (long e0 = 0; e0 < EE; e0 += CE) {
        int ce = (int)((EE - e0 < CE) ? (EE - e0) : CE);
        int mpx = cdiv(cdiv(ce, 128), 8);
        edge_mlp1<<<cdiv(ce, 16), 256, 0, stream>>>(eac + e0 * 16, w1c, b1c, h1c, ce);
        gemm_bt_bias_elu<<<8 * mpx * 8, 256, 0, stream>>>(h1c, w2t, b2c, h2c, ce, 256, 1024, mpx, 3);
        gemm_bt_bias_elu<<<8 * mpx * 8, 256, 0, stream>>>(h2c, w3t, b3c, wec, ce, 1024, 1024, mpx, 3);
        nnconv_msg<<<cdiv((long)ce * 64, 256), 256, 0, stream>>>(wec, xc, src32 + e0, dst32 + e0, agg, ce);
    }
    add_root<<<cdiv((long)NN * 64, 256), 256, 0, stream>>>(xc, rwc, rbc, agg);

    // ---- 3x GINConv (node-chunked MLP) ----
    for (int l = 0; l < 3; ++l) {
        elu_bf16<<<cdiv((long)NN * 64, 256), 256, 0, stream>>>(emb[l], xin, (long)NN * 64);
        hipMemsetAsync(nbr, 0, (size_t)NN * 64 * 4, stream);
        gin_scatter<<<cdiv((long)EE * 64, 256), 256, 0, stream>>>(xin, src32, dst32, nbr);
        for (long n0 = 0; n0 < NN; n0 += CN) {
            int cn = (int)((NN - n0 < CN) ? (NN - n0) : CN);
            int mpx = cdiv(cdiv(cn, 128), 8);
            gin_combine<<<cdiv((long)cn * 64, 256), 256, 0, stream>>>(xin + n0 * 64, nbr + n0 * 64, hin, (long)cn * 64);
            gemm_bt_bias_elu<<<8 * mpx * 2, 256, 0, stream>>>(hin, g1t + l * 256 * 64, gb1c + l * 256, hg1, cn, 64, 256, mpx, 1);
            gemm_bt_bias_elu<<<8 * mpx * 2, 256, 0, stream>>>(hg1, g2t + l * 256 * 256, gb2c + l * 256, hg2, cn, 256, 256, mpx, 1);
            gemm_bt_f32<<<cdiv(cn, 256), 256, 0, stream>>>(hg2, g3t + l * 64 * 256, gb3c + l * 64, emb[l + 1] + n0 * 64, cn, 256);
        }
    }
    write_out<<<cdiv((long)NN * 64, 256), 256, 0, stream>>>(emb[0], emb[1], emb[2], emb[3], out);
}